// Round 1
// baseline (49073.685 us; speedup 1.0000x reference)
//
#include <hip/hip_runtime.h>
#include <math.h>

// Discriminator GRU: B=64, T=1024, S=1024.
// Round 2: persistent-cooperative recurrence.
//   K1: xgT[t][g][u][b] = (batch @ W_ih^T + b_ih (+b_hh for r,z))  (transposed out)
//   K2: ONE cooperative kernel, 1024 steps, hand-rolled grid barrier.
//       256 blocks x 512 thr; block owns 4 units; wave owns 128-k slice; lane=batch.
//       W_hh via wave-uniform (s_load) broadcast, h kept as hT[k][b] (coalesced).
//   K3: out[b] = sigmoid(h_T[b] . W_out + b_out)
// ws layout: [ xgT: 64*1024*3072 f32 (768 MB) | hA: 1024*64 f32 | hB: 1024*64 f32 ]

#define BB 64
#define TT 1024
#define SS 1024
#define GG (3 * SS)
#define NBLK 256

// Barrier state in device globals (NOT ws: ws is poisoned each launch).
// Re-zeroed every graph replay by init_bar_kernel. Separate cachelines.
__device__ unsigned g_cnt[16];
__device__ unsigned g_gen[16];

__global__ void init_bar_kernel() {
  g_cnt[0] = 0u;
  g_gen[0] = 0u;
}

__global__ void zero_kernel(float* __restrict__ p) {
  p[(size_t)blockIdx.x * 1024 + threadIdx.x] = 0.f;
}

// ---------------------------------------------------------------------------
// K1: C layout = xgT[((t*3+g)*S + u)*64 + b].
// 128x128 tile, BK=16, 256 threads, 8x8 microtile. m-tile = 2 timesteps x 64
// batches so the transposed epilogue stores stay 64B-line coalesced
// (4 consecutive ty-lanes cover 64 contiguous bytes of b per unit u).
// ---------------------------------------------------------------------------
__global__ __launch_bounds__(256) void xgates_kernel(
    const float* __restrict__ A, const float* __restrict__ W,
    const float* __restrict__ b_ih, const float* __restrict__ b_hh,
    float* __restrict__ C) {
  __shared__ float As[16][132];  // [k][m], +4 pad
  __shared__ float Bs[16][132];  // [k][n]

  const int tid = threadIdx.x;
  const int n0 = blockIdx.x * 128;  // 24 n-tiles
  const int t0 = blockIdx.y * 2;    // 512 m-tiles; tile = 2 t x 64 b
  const int tx = tid & 15;          // n dir
  const int ty = tid >> 4;          // m dir

  float acc[8][8];
#pragma unroll
  for (int i = 0; i < 8; ++i)
#pragma unroll
    for (int j = 0; j < 8; ++j) acc[i][j] = 0.f;

  for (int kt = 0; kt < SS / 16; ++kt) {
    const int k0 = kt * 16;
#pragma unroll
    for (int i = 0; i < 2; ++i) {
      const int idx = tid + i * 256;  // 0..511
      const int r = idx >> 2;         // tile row 0..127: b = r&63, t = t0+(r>>6)
      const int kq = (idx & 3) * 4;
      float4 av = *(const float4*)&A[((size_t)(r & 63) * TT + t0 + (r >> 6)) * SS + k0 + kq];
      float4 bv = *(const float4*)&W[(size_t)(n0 + r) * SS + k0 + kq];
      As[kq + 0][r] = av.x; As[kq + 1][r] = av.y;
      As[kq + 2][r] = av.z; As[kq + 3][r] = av.w;
      Bs[kq + 0][r] = bv.x; Bs[kq + 1][r] = bv.y;
      Bs[kq + 2][r] = bv.z; Bs[kq + 3][r] = bv.w;
    }
    __syncthreads();
#pragma unroll
    for (int k = 0; k < 16; ++k) {
      float4 a0 = *(const float4*)&As[k][ty * 8];
      float4 a1 = *(const float4*)&As[k][ty * 8 + 4];
      float4 b0 = *(const float4*)&Bs[k][tx * 8];
      float4 b1 = *(const float4*)&Bs[k][tx * 8 + 4];
      float a[8] = {a0.x, a0.y, a0.z, a0.w, a1.x, a1.y, a1.z, a1.w};
      float b[8] = {b0.x, b0.y, b0.z, b0.w, b1.x, b1.y, b1.z, b1.w};
#pragma unroll
      for (int i = 0; i < 8; ++i)
#pragma unroll
        for (int j = 0; j < 8; ++j) acc[i][j] = fmaf(a[i], b[j], acc[i][j]);
    }
    __syncthreads();
  }

  float bias[8];
#pragma unroll
  for (int j = 0; j < 8; ++j) {
    const int n = n0 + tx * 8 + j;
    bias[j] = b_ih[n] + (n < 2 * SS ? b_hh[n] : 0.f);
  }
  // row ty*8+i -> b = (ty&7)*8 + i, t = t0 + (ty>>3)
  const int tt = t0 + (ty >> 3);
  const int bbase = (ty & 7) * 8;
#pragma unroll
  for (int j = 0; j < 8; ++j) {
    const int n = n0 + tx * 8 + j;
    const int g = n >> 10;
    const int u = n & 1023;
    const size_t o = ((size_t)(tt * 3 + g) * SS + u) * 64 + bbase;
    *(float4*)&C[o] = make_float4(acc[0][j] + bias[j], acc[1][j] + bias[j],
                                  acc[2][j] + bias[j], acc[3][j] + bias[j]);
    *(float4*)&C[o + 4] = make_float4(acc[4][j] + bias[j], acc[5][j] + bias[j],
                                      acc[6][j] + bias[j], acc[7][j] + bias[j]);
  }
}

// ---------------------------------------------------------------------------
// Grid barrier: release-fence, single atomic arrive counter, generation spin.
// __threadfence() is an agent-scope fence (wbL2/inv on gfx950) -> h stores are
// visible cross-XCD; the acquire fence invalidates this CU's L1 for all block
// threads (L1 is per-CU). __syncthreads before arrive guarantees vmcnt-drained
// stores from every thread in the block.
// ---------------------------------------------------------------------------
__device__ __forceinline__ void grid_bar(int t) {
  __syncthreads();
  if (threadIdx.x == 0) {
    __threadfence();  // release own (and, post-barrier, block's) stores
    if (atomicAdd(&g_cnt[0], 1u) == NBLK - 1u) {
      __hip_atomic_store(&g_cnt[0], 0u, __ATOMIC_RELAXED,
                         __HIP_MEMORY_SCOPE_AGENT);
      __threadfence();  // order cnt reset before gen bump
      __hip_atomic_store(&g_gen[0], (unsigned)(t + 1), __ATOMIC_RELEASE,
                         __HIP_MEMORY_SCOPE_AGENT);
    } else {
      while (__hip_atomic_load(&g_gen[0], __ATOMIC_ACQUIRE,
                               __HIP_MEMORY_SCOPE_AGENT) < (unsigned)(t + 1))
        __builtin_amdgcn_s_sleep(2);
    }
    __threadfence();  // acquire: invalidate caches before reading new h
  }
  __syncthreads();
}

// ---------------------------------------------------------------------------
// K2: persistent GRU recurrence. 256 blocks x 512 threads (2 waves/SIMD on all
// 256 CUs). Block owns units u0..u0+3; wave w owns k-slice [w*128, w*128+128);
// lane = batch. Each lane accumulates 12 dots (3 gates x 4 units) over its
// k-slice: h loads (coalesced dwords, [k][b] layout) are reused 12x; W comes
// from wave-uniform loads (readfirstlane-forced -> s_load broadcast, zero VGPR
// /LDS cost). 8-way k-split reduced through LDS (stride 13, conflict-free).
// ---------------------------------------------------------------------------
__global__ __launch_bounds__(512, 2) void gru_persistent(
    const float* __restrict__ Whh, const float* __restrict__ xgT,
    const float* __restrict__ bhh, float* __restrict__ hA,
    float* __restrict__ hB) {
  __shared__ float part[8][64][13];  // [wave][b][g*4+r]  26.6 KB
  __shared__ float sums[64][13];     // reduced          3.3 KB

  const int tid = threadIdx.x;
  const int lane = tid & 63;  // batch
  const int u0 = blockIdx.x * 4;
  const int wv = __builtin_amdgcn_readfirstlane(tid >> 6);  // uniform wave id
  const int k0 = wv * 128;

  const float* Wrow[12];  // uniform row bases -> SGPRs
#pragma unroll
  for (int g = 0; g < 3; ++g)
#pragma unroll
    for (int r = 0; r < 4; ++r)
      Wrow[g * 4 + r] = Whh + (size_t)(g * SS + u0 + r) * SS + k0;

  const int ur = (tid >> 6) & 3;  // gate-phase unit (consumed when tid<256)
  const float bhn = bhh[2 * SS + u0 + ur];

  for (int t = 0; t < TT; ++t) {
    const float* __restrict__ hin = (t & 1) ? hB : hA;
    float* __restrict__ hout = (t & 1) ? hA : hB;

    // Prefetch x-gates + h_old for the gate phase; all threads issue
    // (branch-free so the loads hoist above the ~3 us fma phase).
    const size_t xb = ((size_t)(t * 3) * SS + u0 + ur) * 64 + (size_t)lane;
    const float xr = xgT[xb];
    const float xz = xgT[xb + (size_t)SS * 64];
    const float xn = xgT[xb + (size_t)2 * SS * 64];
    const float hold = hin[(u0 + ur) * 64 + lane];

    float acc[12];
#pragma unroll
    for (int i = 0; i < 12; ++i) acc[i] = 0.f;

    for (int kk = 0; kk < 128; kk += 8) {
      float hv[8];
#pragma unroll
      for (int e = 0; e < 8; ++e)
        hv[e] = hin[(size_t)(k0 + kk + e) * 64 + lane];
#pragma unroll
      for (int i = 0; i < 12; ++i) {
        const float* wp = Wrow[i] + kk;
        const float4 wa = *(const float4*)wp;
        const float4 wb = *(const float4*)(wp + 4);
        float a = acc[i];
        a = fmaf(hv[0], wa.x, a);
        a = fmaf(hv[1], wa.y, a);
        a = fmaf(hv[2], wa.z, a);
        a = fmaf(hv[3], wa.w, a);
        a = fmaf(hv[4], wb.x, a);
        a = fmaf(hv[5], wb.y, a);
        a = fmaf(hv[6], wb.z, a);
        a = fmaf(hv[7], wb.w, a);
        acc[i] = a;
      }
    }

    const int w = tid >> 6;
#pragma unroll
    for (int i = 0; i < 12; ++i) part[w][lane][i] = acc[i];
    __syncthreads();

    // Reduce 8 k-split partials: 768 slots (s = si*64+sb), 512 threads.
    {
      const int sb = tid & 63, si = tid >> 6;  // si 0..7
      float v = 0.f;
#pragma unroll
      for (int ww = 0; ww < 8; ++ww) v += part[ww][sb][si];
      sums[sb][si] = v;
    }
    if (tid < 256) {
      const int s2 = tid + 512;
      const int sb = s2 & 63, si = s2 >> 6;  // si 8..11
      float v = 0.f;
#pragma unroll
      for (int ww = 0; ww < 8; ++ww) v += part[ww][sb][si];
      sums[sb][si] = v;
    }
    __syncthreads();

    // Gate math + h update: 256 threads = 64 b x 4 units.
    if (tid < 256) {
      const float ar = sums[lane][ur];
      const float az = sums[lane][4 + ur];
      const float an = sums[lane][8 + ur];
      const float rg = 1.f / (1.f + expf(-(xr + ar)));
      const float zg = 1.f / (1.f + expf(-(xz + az)));
      const float ng = tanhf(xn + rg * (an + bhn));
      hout[(u0 + ur) * 64 + lane] = (1.f - zg) * ng + zg * hold;
    }

    grid_bar(t);
  }
}

// ---------------------------------------------------------------------------
// K3: out[b] = sigmoid(h[b] . W_out + b_out). h is transposed: hT[u][b].
// ---------------------------------------------------------------------------
__global__ __launch_bounds__(256) void out_kernel(
    const float* __restrict__ hT, const float* __restrict__ Wout,
    const float* __restrict__ bout, float* __restrict__ out) {
  const int b = blockIdx.x;
  const int tid = threadIdx.x;
  float s = 0.f;
#pragma unroll
  for (int i = 0; i < 4; ++i) {
    const int u = tid + i * 256;
    s = fmaf(hT[(size_t)u * 64 + b], Wout[u], s);
  }
#pragma unroll
  for (int off = 32; off; off >>= 1) s += __shfl_down(s, off);
  __shared__ float red[4];
  if ((tid & 63) == 0) red[tid >> 6] = s;
  __syncthreads();
  if (tid == 0) {
    const float tot = red[0] + red[1] + red[2] + red[3] + bout[0];
    out[b] = 1.f / (1.f + expf(-tot));
  }
}

// ---------------------------------------------------------------------------
extern "C" void kernel_launch(void* const* d_in, const int* in_sizes, int n_in,
                              void* d_out, int out_size, void* d_ws,
                              size_t ws_size, hipStream_t stream) {
  const float* batch = (const float*)d_in[0];  // [B,T,S]
  const float* W_ih = (const float*)d_in[1];   // [3S,S]
  const float* W_hh = (const float*)d_in[2];   // [3S,S]
  const float* b_ih = (const float*)d_in[3];   // [3S]
  const float* b_hh = (const float*)d_in[4];   // [3S]
  const float* W_out = (const float*)d_in[5];  // [1,S]
  const float* b_out = (const float*)d_in[6];  // [1]
  float* out = (float*)d_out;                  // [B]

  float* xgT = (float*)d_ws;                    // [T][3][S][B] f32 (768 MB)
  float* hA = xgT + (size_t)TT * GG * BB;       // hT [S][B]
  float* hB = hA + (size_t)SS * BB;

  init_bar_kernel<<<1, 1, 0, stream>>>();
  zero_kernel<<<BB, 1024, 0, stream>>>(hA);  // h0 = 0 (1024*64 floats)

  xgates_kernel<<<dim3(GG / 128, (BB * TT) / 128), 256, 0, stream>>>(
      batch, W_ih, b_ih, b_hh, xgT);

  // Persistent recurrence: cooperative launch guarantees co-residency of all
  // 256 blocks (1 block/CU; LDS 30 KB, __launch_bounds__(512,2)).
  {
    const float* a0 = W_hh;
    const float* a1 = xgT;
    const float* a2 = b_hh;
    float* a3 = hA;
    float* a4 = hB;
    void* args[5] = {&a0, &a1, &a2, &a3, &a4};
    hipLaunchCooperativeKernel((const void*)gru_persistent, dim3(NBLK),
                               dim3(512), args, 0, stream);
  }
  // t=1023 (odd) writes hA -> final h in hA

  out_kernel<<<BB, 256, 0, stream>>>(hA, W_out, b_out, out);
}

// Round 2
// 17003.946 us; speedup vs baseline: 2.8860x; 2.8860x over previous
//
#include <hip/hip_runtime.h>
#include <math.h>

// Discriminator GRU: B=64, T=1024, S=1024.
// Round 3: per-step launches (driver-managed coherence; the hand-rolled
// cross-XCD barrier cost ~38 us/step in round 2), with a high-occupancy
// GEMV step kernel.
//   K1: xgT[t][g][u][b] = (batch @ W_ih^T + b_ih (+b_hh for r,z))  (transposed)
//   K2 x1024: 256 blocks x 1024 thr (4 waves/SIMD). Block owns 4 units
//       (12 gate-rows); wave owns k=64 slice; lane=batch. W_hh via
//       wave-uniform s_load broadcast; h kept as hT[k][b] (coalesced, 12x
//       reuse per load); 16-way k-split reduced in LDS (stride 13).
//   K3: out[b] = sigmoid(h_T[b] . W_out + b_out)
// ws layout: [ xgT: 64*1024*3072 f32 (768 MB) | hA: 1024*64 f32 | hB: 1024*64 ]

#define BB 64
#define TT 1024
#define SS 1024
#define GG (3 * SS)

__global__ void zero_kernel(float* __restrict__ p) {
  p[(size_t)blockIdx.x * 1024 + threadIdx.x] = 0.f;
}

// ---------------------------------------------------------------------------
// K1: C layout = xgT[((t*3+g)*S + u)*64 + b].
// 128x128 tile, BK=16, 256 threads, 8x8 microtile. m-tile = 2 timesteps x 64
// batches so the transposed epilogue stores stay 64B-line coalesced.
// ---------------------------------------------------------------------------
__global__ __launch_bounds__(256) void xgates_kernel(
    const float* __restrict__ A, const float* __restrict__ W,
    const float* __restrict__ b_ih, const float* __restrict__ b_hh,
    float* __restrict__ C) {
  __shared__ float As[16][132];  // [k][m], +4 pad
  __shared__ float Bs[16][132];  // [k][n]

  const int tid = threadIdx.x;
  const int n0 = blockIdx.x * 128;  // 24 n-tiles
  const int t0 = blockIdx.y * 2;    // 512 m-tiles; tile = 2 t x 64 b
  const int tx = tid & 15;          // n dir
  const int ty = tid >> 4;          // m dir

  float acc[8][8];
#pragma unroll
  for (int i = 0; i < 8; ++i)
#pragma unroll
    for (int j = 0; j < 8; ++j) acc[i][j] = 0.f;

  for (int kt = 0; kt < SS / 16; ++kt) {
    const int k0 = kt * 16;
#pragma unroll
    for (int i = 0; i < 2; ++i) {
      const int idx = tid + i * 256;  // 0..511
      const int r = idx >> 2;         // tile row 0..127: b = r&63, t = t0+(r>>6)
      const int kq = (idx & 3) * 4;
      float4 av = *(const float4*)&A[((size_t)(r & 63) * TT + t0 + (r >> 6)) * SS + k0 + kq];
      float4 bv = *(const float4*)&W[(size_t)(n0 + r) * SS + k0 + kq];
      As[kq + 0][r] = av.x; As[kq + 1][r] = av.y;
      As[kq + 2][r] = av.z; As[kq + 3][r] = av.w;
      Bs[kq + 0][r] = bv.x; Bs[kq + 1][r] = bv.y;
      Bs[kq + 2][r] = bv.z; Bs[kq + 3][r] = bv.w;
    }
    __syncthreads();
#pragma unroll
    for (int k = 0; k < 16; ++k) {
      float4 a0 = *(const float4*)&As[k][ty * 8];
      float4 a1 = *(const float4*)&As[k][ty * 8 + 4];
      float4 b0 = *(const float4*)&Bs[k][tx * 8];
      float4 b1 = *(const float4*)&Bs[k][tx * 8 + 4];
      float a[8] = {a0.x, a0.y, a0.z, a0.w, a1.x, a1.y, a1.z, a1.w};
      float b[8] = {b0.x, b0.y, b0.z, b0.w, b1.x, b1.y, b1.z, b1.w};
#pragma unroll
      for (int i = 0; i < 8; ++i)
#pragma unroll
        for (int j = 0; j < 8; ++j) acc[i][j] = fmaf(a[i], b[j], acc[i][j]);
    }
    __syncthreads();
  }

  float bias[8];
#pragma unroll
  for (int j = 0; j < 8; ++j) {
    const int n = n0 + tx * 8 + j;
    bias[j] = b_ih[n] + (n < 2 * SS ? b_hh[n] : 0.f);
  }
  // row ty*8+i -> b = (ty&7)*8 + i, t = t0 + (ty>>3)
  const int tt = t0 + (ty >> 3);
  const int bbase = (ty & 7) * 8;
#pragma unroll
  for (int j = 0; j < 8; ++j) {
    const int n = n0 + tx * 8 + j;
    const int g = n >> 10;
    const int u = n & 1023;
    const size_t o = ((size_t)(tt * 3 + g) * SS + u) * 64 + bbase;
    *(float4*)&C[o] = make_float4(acc[0][j] + bias[j], acc[1][j] + bias[j],
                                  acc[2][j] + bias[j], acc[3][j] + bias[j]);
    *(float4*)&C[o + 4] = make_float4(acc[4][j] + bias[j], acc[5][j] + bias[j],
                                      acc[6][j] + bias[j], acc[7][j] + bias[j]);
  }
}

// ---------------------------------------------------------------------------
// K2: one GRU step. 256 blocks x 1024 threads = 16 waves (4 waves/SIMD, all
// 256 CUs). Block owns units u0..u0+3 (12 gate-rows); wave wv owns k-slice
// [wv*64, wv*64+64); lane = batch. Each lane accumulates 12 dots over its
// k-slice: h loads (coalesced dwords, hT[k][b] layout) are reused 12x; W is
// wave-uniform (readfirstlane-forced -> s_load broadcast, scalar pipe, no
// VGPR/LDS cost). 16-way k-split reduced through LDS (stride 13, no bank
// conflicts), then gate math + h update on 256 threads (64 b x 4 units).
// ---------------------------------------------------------------------------
__global__ __launch_bounds__(1024) void gru_step_kernel(
    const float* __restrict__ hin, float* __restrict__ hout,
    const float* __restrict__ Whh, const float* __restrict__ xgT,
    const float* __restrict__ bhh, const int t) {
  __shared__ float part[16][64][13];  // [wave][b][g*4+r]  53.2 KB
  __shared__ float sums[64][13];      //                    3.3 KB

  const int tid = threadIdx.x;
  const int lane = tid & 63;  // batch
  const int u0 = blockIdx.x * 4;
  const int wv = __builtin_amdgcn_readfirstlane(tid >> 6);  // uniform 0..15
  const int k0 = wv * 64;

  const float* Wrow[12];  // uniform row bases -> SGPRs
#pragma unroll
  for (int g = 0; g < 3; ++g)
#pragma unroll
    for (int r = 0; r < 4; ++r)
      Wrow[g * 4 + r] = Whh + (size_t)(g * SS + u0 + r) * SS + k0;

  // Prefetch gate-phase inputs early (waves 0..3 only); loads stay
  // outstanding across the fma phase.
  float xr = 0.f, xz = 0.f, xn = 0.f, hold = 0.f, bhn = 0.f;
  if (tid < 256) {
    const int ur = tid >> 6;  // 0..3
    const size_t xb = ((size_t)(t * 3) * SS + u0 + ur) * 64 + (size_t)lane;
    xr = xgT[xb];
    xz = xgT[xb + (size_t)SS * 64];
    xn = xgT[xb + (size_t)2 * SS * 64];
    hold = hin[(u0 + ur) * 64 + lane];
    bhn = bhh[2 * SS + u0 + ur];
  }

  float acc[12];
#pragma unroll
  for (int i = 0; i < 12; ++i) acc[i] = 0.f;

  for (int kk = 0; kk < 64; kk += 8) {
    float hv[8];
#pragma unroll
    for (int e = 0; e < 8; ++e)
      hv[e] = hin[(size_t)(k0 + kk + e) * 64 + lane];
#pragma unroll
    for (int i = 0; i < 12; ++i) {
      const float* wp = Wrow[i] + kk;
      const float4 wa = *(const float4*)wp;
      const float4 wb = *(const float4*)(wp + 4);
      float a = acc[i];
      a = fmaf(hv[0], wa.x, a);
      a = fmaf(hv[1], wa.y, a);
      a = fmaf(hv[2], wa.z, a);
      a = fmaf(hv[3], wa.w, a);
      a = fmaf(hv[4], wb.x, a);
      a = fmaf(hv[5], wb.y, a);
      a = fmaf(hv[6], wb.z, a);
      a = fmaf(hv[7], wb.w, a);
      acc[i] = a;
    }
  }

  const int w = tid >> 6;
#pragma unroll
  for (int i = 0; i < 12; ++i) part[w][lane][i] = acc[i];
  __syncthreads();

  // Reduce 16 k-split partials: 768 sums, threads 0..767 (one sum each).
  // part[ww][sb][si]: lane stride 13 dwords -> 2 lanes/bank (free).
  if (tid < 768) {
    const int sb = tid & 63, si = tid >> 6;  // si 0..11
    float v = 0.f;
#pragma unroll
    for (int ww = 0; ww < 16; ++ww) v += part[ww][sb][si];
    sums[sb][si] = v;
  }
  __syncthreads();

  // Gate math + h update: 256 threads = 64 b x 4 units.
  if (tid < 256) {
    const int ur = tid >> 6;
    const float ar = sums[lane][ur];
    const float az = sums[lane][4 + ur];
    const float an = sums[lane][8 + ur];
    const float rg = 1.f / (1.f + expf(-(xr + ar)));
    const float zg = 1.f / (1.f + expf(-(xz + az)));
    const float ng = tanhf(xn + rg * (an + bhn));
    hout[(u0 + ur) * 64 + lane] = (1.f - zg) * ng + zg * hold;
  }
}

// ---------------------------------------------------------------------------
// K3: out[b] = sigmoid(h[b] . W_out + b_out). h is transposed: hT[u][b].
// ---------------------------------------------------------------------------
__global__ __launch_bounds__(256) void out_kernel(
    const float* __restrict__ hT, const float* __restrict__ Wout,
    const float* __restrict__ bout, float* __restrict__ out) {
  const int b = blockIdx.x;
  const int tid = threadIdx.x;
  float s = 0.f;
#pragma unroll
  for (int i = 0; i < 4; ++i) {
    const int u = tid + i * 256;
    s = fmaf(hT[(size_t)u * 64 + b], Wout[u], s);
  }
#pragma unroll
  for (int off = 32; off; off >>= 1) s += __shfl_down(s, off);
  __shared__ float red[4];
  if ((tid & 63) == 0) red[tid >> 6] = s;
  __syncthreads();
  if (tid == 0) {
    const float tot = red[0] + red[1] + red[2] + red[3] + bout[0];
    out[b] = 1.f / (1.f + expf(-tot));
  }
}

// ---------------------------------------------------------------------------
extern "C" void kernel_launch(void* const* d_in, const int* in_sizes, int n_in,
                              void* d_out, int out_size, void* d_ws,
                              size_t ws_size, hipStream_t stream) {
  const float* batch = (const float*)d_in[0];  // [B,T,S]
  const float* W_ih = (const float*)d_in[1];   // [3S,S]
  const float* W_hh = (const float*)d_in[2];   // [3S,S]
  const float* b_ih = (const float*)d_in[3];   // [3S]
  const float* b_hh = (const float*)d_in[4];   // [3S]
  const float* W_out = (const float*)d_in[5];  // [1,S]
  const float* b_out = (const float*)d_in[6];  // [1]
  float* out = (float*)d_out;                  // [B]

  float* xgT = (float*)d_ws;               // [T][3][S][B] f32 (768 MB)
  float* hA = xgT + (size_t)TT * GG * BB;  // hT [S][B]
  float* hB = hA + (size_t)SS * BB;

  zero_kernel<<<BB, 1024, 0, stream>>>(hA);  // h0 = 0 (1024*64 floats)

  xgates_kernel<<<dim3(GG / 128, (BB * TT) / 128), 256, 0, stream>>>(
      batch, W_ih, b_ih, b_hh, xgT);

  // Recurrence: 1024 sequential steps, double-buffered h.
  for (int t = 0; t < TT; ++t) {
    const float* hp = (t & 1) ? hB : hA;
    float* hn = (t & 1) ? hA : hB;
    gru_step_kernel<<<256, 1024, 0, stream>>>(hp, hn, W_hh, xgT, b_hh, t);
  }
  // t=1023 (odd) writes hA -> final h in hA

  out_kernel<<<BB, 256, 0, stream>>>(hA, W_out, b_out, out);
}